// Round 5
// baseline (606.763 us; speedup 1.0000x reference)
//
#include <hip/hip_runtime.h>
#include <math.h>

// ---------------- problem constants ----------------
#define DD 128
#define SPLIT 50000
#define NN1 50000
#define NN2 30000
#define NN3 10000
#define EE0 500000
#define EE1 300000
#define EE2 100000
#define EALL (EE0 + EE1 + EE2)
#define NALL (NN1 + NN2 + NN3)   // 90000
#define B1 50000
#define B2 80000
#define NEG 0.2f

typedef __attribute__((ext_vector_type(8))) short bf16x8;
typedef __attribute__((ext_vector_type(4))) float f32x4;

// round-to-nearest-even f32 -> bf16 bits
static __device__ __forceinline__ unsigned short f2bf(float x) {
  unsigned u = __float_as_uint(x);
  unsigned r = (u + 0x7FFFu + ((u >> 16) & 1u)) >> 16;
  return (unsigned short)r;
}
static __device__ __forceinline__ float bf2f(unsigned short b) {
  return __uint_as_float(((unsigned)b) << 16);
}

// ================= fused CSR build (3 graphs concatenated) =================
__global__ __launch_bounds__(256) void hist_kernel(
    const int* __restrict__ dst0, const int* __restrict__ dst1,
    const int* __restrict__ dst2, int* __restrict__ counts)
{
  for (int e = blockIdx.x * 256 + threadIdx.x; e < EALL; e += gridDim.x * 256) {
    int d;
    if (e < EE0) d = dst0[e];
    else if (e < EE0 + EE1) d = B1 + dst1[e - EE0];
    else d = B2 + dst2[e - EE0 - EE1];
    atomicAdd(&counts[d], 1);
  }
}

__global__ __launch_bounds__(256) void scan1_kernel(
    const int* __restrict__ counts, int* __restrict__ rp1,
    int* __restrict__ partial, int n)
{
  __shared__ int s[256];
  int t = threadIdx.x;
  int i = blockIdx.x * 256 + t;
  int v = (i < n) ? counts[i] : 0;
  s[t] = v; __syncthreads();
  for (int off = 1; off < 256; off <<= 1) {
    int tv = (t >= off) ? s[t - off] : 0;
    __syncthreads();
    s[t] += tv;
    __syncthreads();
  }
  if (i < n) rp1[i] = s[t];
  if (t == 255) partial[blockIdx.x] = s[255];
}

__global__ __launch_bounds__(256) void scan2_kernel(int* __restrict__ partial, int nb)
{
  __shared__ int s[256];
  int t = threadIdx.x;
  int carry = 0;
  for (int base = 0; base < nb; base += 256) {
    int i = base + t;
    int v = (i < nb) ? partial[i] : 0;
    s[t] = v; __syncthreads();
    for (int off = 1; off < 256; off <<= 1) {
      int tv = (t >= off) ? s[t - off] : 0;
      __syncthreads();
      s[t] += tv;
      __syncthreads();
    }
    int ex = carry + ((t == 0) ? 0 : s[t - 1]);
    if (i < nb) partial[i] = ex;
    int tot = s[255];
    __syncthreads();
    carry += tot;
  }
}

__global__ __launch_bounds__(256) void scan3_kernel(
    int* __restrict__ rp, const int* __restrict__ partial, int n)
{
  int i = blockIdx.x * 256 + threadIdx.x;
  if (i < n) rp[i + 1] += partial[i >> 8];
  if (i == 0) rp[0] = 0;
}

__global__ __launch_bounds__(256) void fill_kernel(
    const int* __restrict__ dst0, const int* __restrict__ src0,
    const int* __restrict__ dst1, const int* __restrict__ src1,
    const int* __restrict__ dst2, const int* __restrict__ src2,
    const int* __restrict__ etyp, int* __restrict__ cursor,
    int* __restrict__ vals)
{
  for (int e = blockIdx.x * 256 + threadIdx.x; e < EALL; e += gridDim.x * 256) {
    int d, v;
    if (e < EE0) { d = dst0[e]; v = src0[e]; }
    else if (e < EE0 + EE1) {
      int k = e - EE0;
      d = B1 + dst1[k]; v = src1[k] | (etyp[k] << 17);
    } else {
      int k = e - EE0 - EE1;
      d = B2 + dst2[k]; v = src2[k];
    }
    int slot = atomicAdd(&cursor[d], 1);
    vals[slot] = v;
  }
}

// ================= weight prep: W[128][128] f32 -> transposed hi/lo bf16 =======
struct W9 { const float* w[9]; };
__global__ __launch_bounds__(256) void wprep_kernel(W9 srcs, unsigned short* out)
{
  int m = blockIdx.y;
  const float* W = srcs.w[m];
  unsigned short* hi = out + (size_t)m * 32768;
  unsigned short* lo = hi + 16384;
  for (int i = blockIdx.x * 256 + threadIdx.x; i < 16384; i += gridDim.x * 256) {
    int k = i >> 7, c = i & 127;
    float a = W[i];
    unsigned short h = f2bf(a);
    hi[c * DD + k] = h;
    lo[c * DD + k] = f2bf(a - bf2f(h));
  }
}

// ================= layer 0: CSR gather-sum of x rows =================
__global__ __launch_bounds__(256) void agg0_kernel(
    const float* __restrict__ x, const int* __restrict__ rp,
    const int* __restrict__ vals, float* __restrict__ acc, float* __restrict__ deg)
{
  int d = blockIdx.x * 4 + (threadIdx.x >> 6);
  if (d >= NN1) return;
  int lane = threadIdx.x & 63;
  int l32 = lane & 31, half = lane >> 5;
  int beg = rp[d], end = rp[d + 1];
  const float4* x4 = (const float4*)x;
  float4 a0 = {0.f, 0.f, 0.f, 0.f}, a1 = {0.f, 0.f, 0.f, 0.f};
  int j = beg + half;
  for (; j + 2 < end; j += 4) {
    int s0 = vals[j], s1 = vals[j + 2];
    if (s0 >= SPLIT) {
      float4 v = x4[(size_t)(s0 - SPLIT) * 32 + l32];
      a0.x += v.x; a0.y += v.y; a0.z += v.z; a0.w += v.w;
    }
    if (s1 >= SPLIT) {
      float4 v = x4[(size_t)(s1 - SPLIT) * 32 + l32];
      a1.x += v.x; a1.y += v.y; a1.z += v.z; a1.w += v.w;
    }
  }
  if (j < end) {
    int s0 = vals[j];
    if (s0 >= SPLIT) {
      float4 v = x4[(size_t)(s0 - SPLIT) * 32 + l32];
      a0.x += v.x; a0.y += v.y; a0.z += v.z; a0.w += v.w;
    }
  }
  a0.x += a1.x; a0.y += a1.y; a0.z += a1.z; a0.w += a1.w;
  a0.x += __shfl(a0.x, l32 + 32);
  a0.y += __shfl(a0.y, l32 + 32);
  a0.z += __shfl(a0.z, l32 + 32);
  a0.w += __shfl(a0.w, l32 + 32);
  if (half == 0) {
    ((float4*)acc)[(size_t)d * 32 + l32] = a0;
    if (l32 == 0) deg[d] = (float)(end - beg);
  }
}

// ---- f32 LDS GEMM kept only for the two 65-row table projections ----
__global__ __launch_bounds__(256) void gemm128_kernel(
    const float* __restrict__ A, const float* __restrict__ W,
    float* __restrict__ C, int N, const float* __restrict__ deg)
{
  __shared__ float Al[64 * 128];
  __shared__ float Wl[64 * 128];
  int t = threadIdx.x;
  int cg = t & 31;
  int rg = t >> 5;
  int r0 = blockIdx.x << 6;
  int nrows = N - r0; if (nrows > 64) nrows = 64;

  const float4* Ag = (const float4*)(A + (size_t)r0 * DD);
  float4* Al4 = (float4*)Al;
  for (int i = t; i < nrows * 32; i += 256) Al4[i] = Ag[i];

  float acc[8][4] = {};
  const float4* W4 = (const float4*)W;
  float4* Wl4 = (float4*)Wl;
  const float4* Al4c = (const float4*)Al;

  for (int half = 0; half < 2; ++half) {
    __syncthreads();
    for (int i = t; i < 2048; i += 256) Wl4[i] = W4[half * 2048 + i];
    __syncthreads();
    const float4* Wl4c = (const float4*)Wl;
    int kb4 = half * 16;
    for (int k4 = 0; k4 < 16; ++k4) {
      float4 w0 = Wl4c[(k4 * 4 + 0) * 32 + cg];
      float4 w1 = Wl4c[(k4 * 4 + 1) * 32 + cg];
      float4 w2 = Wl4c[(k4 * 4 + 2) * 32 + cg];
      float4 w3 = Wl4c[(k4 * 4 + 3) * 32 + cg];
#pragma unroll
      for (int r = 0; r < 8; ++r) {
        float4 a = Al4c[(rg * 8 + r) * 32 + kb4 + k4];
        acc[r][0] = fmaf(a.x, w0.x, acc[r][0]);
        acc[r][1] = fmaf(a.x, w0.y, acc[r][1]);
        acc[r][2] = fmaf(a.x, w0.z, acc[r][2]);
        acc[r][3] = fmaf(a.x, w0.w, acc[r][3]);
        acc[r][0] = fmaf(a.y, w1.x, acc[r][0]);
        acc[r][1] = fmaf(a.y, w1.y, acc[r][1]);
        acc[r][2] = fmaf(a.y, w1.z, acc[r][2]);
        acc[r][3] = fmaf(a.y, w1.w, acc[r][3]);
        acc[r][0] = fmaf(a.z, w2.x, acc[r][0]);
        acc[r][1] = fmaf(a.z, w2.y, acc[r][1]);
        acc[r][2] = fmaf(a.z, w2.z, acc[r][2]);
        acc[r][3] = fmaf(a.z, w2.w, acc[r][3]);
        acc[r][0] = fmaf(a.w, w3.x, acc[r][0]);
        acc[r][1] = fmaf(a.w, w3.y, acc[r][1]);
        acc[r][2] = fmaf(a.w, w3.z, acc[r][2]);
        acc[r][3] = fmaf(a.w, w3.w, acc[r][3]);
      }
    }
  }

#pragma unroll
  for (int r = 0; r < 8; ++r) {
    int rr = rg * 8 + r;
    if (rr < nrows) {
      float sc = 1.0f;
      if (deg) sc = 0.5f / (deg[r0 + rr] + 1e-16f);
      float4 o;
      o.x = acc[r][0] * sc; o.y = acc[r][1] * sc;
      o.z = acc[r][2] * sc; o.w = acc[r][3] * sc;
      ((float4*)(C + (size_t)(r0 + rr) * DD))[cg] = o;
    }
  }
}

// ======== MFMA split-bf16 GEMM, up to 4 outputs sharing A ========
// C_i = [bn](A) @ W_i ; split-bf16: C = Ah@Wh + Ah@Wl + Al@Wh (f32 accum).
// Block = 4 waves; wave owns 16 rows; no LDS. Wt layouts are [col][k] bf16.
__global__ __launch_bounds__(256) void mfma_gemm4_kernel(
    const float* __restrict__ A,
    const float* __restrict__ SC, const float* __restrict__ SH,
    const unsigned short* __restrict__ WP,
    int w0, int w1, int w2, int w3,
    float* __restrict__ C0, float* __restrict__ C1,
    float* __restrict__ C2, float* __restrict__ C3,
    int N0, int N1, int N2, int N3,
    const float* __restrict__ deg)
{
  int t = threadIdx.x;
  int l = t & 63;
  int wl = t >> 6;
  int r0 = blockIdx.x << 6;
  int rbase = r0 + wl * 16 + (l & 15);
  int r_ld = rbase < N0 ? rbase : (N0 - 1);
  int kg = (l >> 4) << 3;          // 0/8/16/24 within 32-k step

  // load + (optional BN) + split A fragments for 4 k-steps
  bf16x8 Ah[4], Al[4];
#pragma unroll
  for (int ks = 0; ks < 4; ++ks) {
    int k0 = ks * 32 + kg;
    const float4* ap = (const float4*)(A + (size_t)r_ld * DD + k0);
    float4 x0 = ap[0], x1 = ap[1];
    float av[8] = {x0.x, x0.y, x0.z, x0.w, x1.x, x1.y, x1.z, x1.w};
    if (SC) {
      const float4* scp = (const float4*)(SC + k0);
      const float4* shp = (const float4*)(SH + k0);
      float4 s0 = scp[0], s1 = scp[1], h0 = shp[0], h1 = shp[1];
      av[0] = fmaf(av[0], s0.x, h0.x);
      av[1] = fmaf(av[1], s0.y, h0.y);
      av[2] = fmaf(av[2], s0.z, h0.z);
      av[3] = fmaf(av[3], s0.w, h0.w);
      av[4] = fmaf(av[4], s1.x, h1.x);
      av[5] = fmaf(av[5], s1.y, h1.y);
      av[6] = fmaf(av[6], s1.z, h1.z);
      av[7] = fmaf(av[7], s1.w, h1.w);
    }
#pragma unroll
    for (int j = 0; j < 8; ++j) {
      unsigned short h = f2bf(av[j]);
      Ah[ks][j] = (short)h;
      Al[ks][j] = (short)f2bf(av[j] - bf2f(h));
    }
  }

  auto do_out = [&](int widx, float* C, int N, bool useDeg) {
    if (widx < 0 || r0 >= N) return;
    const unsigned short* Wh = WP + (size_t)widx * 32768;
    const unsigned short* Wl = Wh + 16384;
    f32x4 acc[8];
#pragma unroll
    for (int ct = 0; ct < 8; ++ct) acc[ct] = (f32x4){0.f, 0.f, 0.f, 0.f};
#pragma unroll
    for (int ks = 0; ks < 4; ++ks) {
      int koff = ks * 32 + kg;
#pragma unroll
      for (int ct = 0; ct < 8; ++ct) {
        int col = ct * 16 + (l & 15);
        bf16x8 bh = *(const bf16x8*)(Wh + (size_t)col * DD + koff);
        bf16x8 bl = *(const bf16x8*)(Wl + (size_t)col * DD + koff);
        acc[ct] = __builtin_amdgcn_mfma_f32_16x16x32_bf16(Ah[ks], bh, acc[ct], 0, 0, 0);
        acc[ct] = __builtin_amdgcn_mfma_f32_16x16x32_bf16(Al[ks], bh, acc[ct], 0, 0, 0);
        acc[ct] = __builtin_amdgcn_mfma_f32_16x16x32_bf16(Ah[ks], bl, acc[ct], 0, 0, 0);
      }
    }
    int rw = r0 + wl * 16 + ((l >> 4) << 2);   // first of this lane's 4 rows
    float scl[4] = {1.f, 1.f, 1.f, 1.f};
    if (useDeg) {
#pragma unroll
      for (int r = 0; r < 4; ++r) {
        int rr = rw + r; if (rr > N - 1) rr = N - 1;
        scl[r] = 0.5f / (deg[rr] + 1e-16f);
      }
    }
#pragma unroll
    for (int ct = 0; ct < 8; ++ct) {
      int col = ct * 16 + (l & 15);
#pragma unroll
      for (int r = 0; r < 4; ++r) {
        int row = rw + r;
        if (row < N) C[(size_t)row * DD + col] = acc[ct][r] * scl[r];
      }
    }
  };

  do_out(w0, C0, N0, deg != nullptr);
  do_out(w1, C1, N1, false);
  do_out(w2, C2, N2, false);
  do_out(w3, C3, N3, false);
}

// ---------------- BatchNorm stats + finalize ----------------
__global__ __launch_bounds__(256) void bn_stats_kernel(
    const float* __restrict__ H, float* __restrict__ sums)
{
  int t = threadIdx.x;
  int col = t & 127;
  float s = 0.f, q = 0.f;
  for (int r = blockIdx.x * 2 + (t >> 7); r < NN1; r += gridDim.x * 2) {
    float v = H[(size_t)r * DD + col];
    s += v; q += v * v;
  }
  __shared__ float ls[256], lq[256];
  ls[t] = s; lq[t] = q;
  __syncthreads();
  if (t < 128) {
    atomicAdd(&sums[col], ls[t] + ls[t + 128]);
    atomicAdd(&sums[128 + col], lq[t] + lq[t + 128]);
  }
}

__global__ __launch_bounds__(128) void bn_finalize_kernel(
    const float* __restrict__ sums, const float* __restrict__ g,
    const float* __restrict__ b, float* __restrict__ SC, float* __restrict__ SH)
{
  int c = threadIdx.x;
  const float invN = 1.0f / (float)NN1;
  float mu = sums[c] * invN;
  float var = sums[128 + c] * invN - mu * mu;
  float rs = rsqrtf(var + 1e-5f);
  float sc = rs * g[c];
  SC[c] = sc;
  SH[c] = b[c] - mu * sc;
}

// ========== fused flash-attention over value-CSR ==========
__global__ __launch_bounds__(256) void attn_kernel(
    const float* __restrict__ Q, const float* __restrict__ K,
    const float* __restrict__ V, const float* __restrict__ EKT,
    const float* __restrict__ EVT, const int* __restrict__ rp,
    const int* __restrict__ vals, const float* __restrict__ Spre,
    float* __restrict__ Out, int Nt)
{
  int d = blockIdx.x * 4 + (threadIdx.x >> 6);
  if (d >= Nt) return;
  int lane = threadIdx.x & 63;
  int l32 = lane & 31, half = lane >> 5;

  const float4* Q4 = (const float4*)Q;
  const float4* K4 = (const float4*)K;
  const float4* V4 = (const float4*)V;
  float4 q = Q4[(size_t)d * 32 + l32];

  float m = -INFINITY, ss = 0.f;
  float4 o = {0.f, 0.f, 0.f, 0.f};

  int beg = rp[d], end = rp[d + 1];
  for (int j = beg + half; j < end; j += 2) {
    int pv = vals[j];
    float4 kk, vv;
    if (EKT) {
      int s = pv & 0x1FFFF, ty = pv >> 17;
      kk = K4[(size_t)s * 32 + l32];
      vv = V4[(size_t)s * 32 + l32];
      float4 ek = ((const float4*)EKT)[(size_t)ty * 32 + l32];
      float4 ev = ((const float4*)EVT)[(size_t)ty * 32 + l32];
      kk.x += ek.x; kk.y += ek.y; kk.z += ek.z; kk.w += ek.w;
      vv.x += ev.x; vv.y += ev.y; vv.z += ev.z; vv.w += ev.w;
    } else {
      kk = K4[(size_t)pv * 32 + l32];
      vv = V4[(size_t)pv * 32 + l32];
    }
    float p = q.x * kk.x + q.y * kk.y + q.z * kk.z + q.w * kk.w;
    p += __shfl_xor(p, 1);
    p += __shfl_xor(p, 2);
    float lg = p * 0.25f;
    lg = (lg >= 0.f) ? lg : NEG * lg;
    float nm = fmaxf(m, lg);
    float w = __expf(m - nm);
    float a = __expf(lg - nm);
    ss = ss * w + a;
    o.x = o.x * w + a * vv.x;
    o.y = o.y * w + a * vv.y;
    o.z = o.z * w + a * vv.z;
    o.w = o.w * w + a * vv.w;
    m = nm;
  }

  float mp = __shfl_xor(m, 32);
  float sp = __shfl_xor(ss, 32);
  float4 op;
  op.x = __shfl_xor(o.x, 32);
  op.y = __shfl_xor(o.y, 32);
  op.z = __shfl_xor(o.z, 32);
  op.w = __shfl_xor(o.w, 32);
  float nm = fmaxf(m, mp);
  if (nm == -INFINITY) nm = 0.f;
  float w = __expf(m - nm);
  float wp = __expf(mp - nm);
  float sT = ss * w + sp * wp;
  float inv = 1.0f / (sT + 1e-16f);
  float4 res;
  res.x = (o.x * w + op.x * wp) * inv;
  res.y = (o.y * w + op.y * wp) * inv;
  res.z = (o.z * w + op.z * wp) * inv;
  res.w = (o.w * w + op.w * wp) * inv;

  if (half == 0) {
    float4 sr = ((const float4*)Spre)[(size_t)d * 32 + l32];
    float4 ot;
    ot.x = 0.5f * (sr.x + res.x);
    ot.y = 0.5f * (sr.y + res.y);
    ot.z = 0.5f * (sr.z + res.z);
    ot.w = 0.5f * (sr.w + res.w);
    ((float4*)Out)[(size_t)d * 32 + l32] = ot;
  }
}

extern "C" void kernel_launch(void* const* d_in, const int* in_sizes, int n_in,
                              void* d_out, int out_size, void* d_ws, size_t ws_size,
                              hipStream_t stream)
{
  const float* x   = (const float*)d_in[0];
  const float* tt  = (const float*)d_in[1];
  const float* at  = (const float*)d_in[2];
  const float* Wv0 = (const float*)d_in[5];
  const float* Wq1 = (const float*)d_in[7];
  const float* Wk1 = (const float*)d_in[8];
  const float* Wv1 = (const float*)d_in[9];
  const float* Ws1 = (const float*)d_in[10];
  const float* Wek1= (const float*)d_in[11];
  const float* Wev1= (const float*)d_in[12];
  const float* Wq2 = (const float*)d_in[13];
  const float* Wk2 = (const float*)d_in[14];
  const float* Wv2 = (const float*)d_in[15];
  const float* Ws2 = (const float*)d_in[16];
  const float* g0  = (const float*)d_in[17];
  const float* b0  = (const float*)d_in[18];
  const int* src0 = (const int*)d_in[19];
  const int* dst0 = (const int*)d_in[20];
  const int* src1 = (const int*)d_in[21];
  const int* dst1 = (const int*)d_in[22];
  const int* src2 = (const int*)d_in[23];
  const int* dst2 = (const int*)d_in[24];
  const int* etyp = (const int*)d_in[25];

  float* ws = (float*)d_ws;

  // ---- float workspace layout ----
  const size_t O_K1  = 0;          // 6.40M : acc0, then k1
  const size_t O_V1  = 6400000;    // 6.40M : v1
  const size_t O_Q1  = 12800000;   // 3.84M : q1
  const size_t O_H2  = 16640000;   // 3.84M : s1 prefill -> h2 (attn in place)
  const size_t O_DEG = 20480000;   // 50K
  const size_t O_EK  = 20530000;   // 8320
  const size_t O_EV  = 20538320;   // 8320
  const size_t O_BN  = 20546640;   // 256
  const size_t O_SC  = 20546896;   // 128
  const size_t O_SH  = 20547024;   // 128
  const size_t O_H1  = 20547152;   // 6.40M -> end 26,947,152
  // layer-2 overlays:
  const size_t O_K2  = 0;          // 3.84M
  const size_t O_V2  = 3840000;    // 3.84M
  const size_t O_Q2  = 7680000;    // 1.28M
  const size_t O_S2  = 8960000;    // 1.28M
  // ---- int workspace ----
  int* wi   = (int*)(ws + 26947152);
  int* RP   = wi;                  // 90001
  int* VALS = wi + 90001;          // 900000
  int* CNT  = wi + 990001;         // 90000
  int* PART = wi + 1080001;        // 512
  unsigned short* WPREP = (unsigned short*)(wi + 1080520); // 9*32768 ushort

  // ================= weight prep (9 matrices) =================
  // idx: 0 Wv0 | 1 Wk1 2 Wv1 3 Wq1 4 Ws1 | 5 Wk2 6 Wv2 7 Wq2 8 Ws2
  W9 w9;
  w9.w[0] = Wv0;
  w9.w[1] = Wk1; w9.w[2] = Wv1; w9.w[3] = Wq1; w9.w[4] = Ws1;
  w9.w[5] = Wk2; w9.w[6] = Wv2; w9.w[7] = Wq2; w9.w[8] = Ws2;
  wprep_kernel<<<dim3(8, 9), 256, 0, stream>>>(w9, WPREP);

  // ================= fused CSR build =================
  hipMemsetAsync(CNT, 0, (size_t)NALL * 4, stream);
  hist_kernel<<<3516, 256, 0, stream>>>(dst0, dst1, dst2, CNT);
  int nb = (NALL + 255) / 256;     // 352
  scan1_kernel<<<nb, 256, 0, stream>>>(CNT, RP + 1, PART, NALL);
  scan2_kernel<<<1, 256, 0, stream>>>(PART, nb);
  scan3_kernel<<<nb, 256, 0, stream>>>(RP, PART, NALL);
  hipMemcpyAsync(CNT, RP, (size_t)NALL * 4, hipMemcpyDeviceToDevice, stream);
  fill_kernel<<<3516, 256, 0, stream>>>(dst0, src0, dst1, src1, dst2, src2,
                                        etyp, CNT, VALS);

  hipMemsetAsync(ws + O_BN, 0, (size_t)256 * 4, stream);

  // ================= layer 0 =================
  agg0_kernel<<<(NN1 + 3) / 4, 256, 0, stream>>>(x, RP, VALS, ws + O_K1, ws + O_DEG);
  // h1 = 0.5*(acc0 @ Wv0)/(deg+1e-16)
  mfma_gemm4_kernel<<<(NN1 + 63) / 64, 256, 0, stream>>>(
      ws + O_K1, nullptr, nullptr, WPREP,
      0, -1, -1, -1,
      ws + O_H1, nullptr, nullptr, nullptr,
      NN1, 0, 0, 0, ws + O_DEG);
  bn_stats_kernel<<<512, 256, 0, stream>>>(ws + O_H1, ws + O_BN);
  bn_finalize_kernel<<<1, 128, 0, stream>>>(ws + O_BN, g0, b0, ws + O_SC, ws + O_SH);

  // ================= layer 1 (BN folded into A) =================
  mfma_gemm4_kernel<<<(NN1 + 63) / 64, 256, 0, stream>>>(
      ws + O_H1, ws + O_SC, ws + O_SH, WPREP,
      1, 2, 3, 4,
      ws + O_K1, ws + O_V1, ws + O_Q1, ws + O_H2,
      NN1, NN1, NN2, NN2, nullptr);
  gemm128_kernel<<<2, 256, 0, stream>>>(tt, Wek1, ws + O_EK, 65, nullptr);
  gemm128_kernel<<<2, 256, 0, stream>>>(at, Wev1, ws + O_EV, 65, nullptr);

  attn_kernel<<<(NN2 + 3) / 4, 256, 0, stream>>>(
      ws + O_Q1, ws + O_K1, ws + O_V1, ws + O_EK, ws + O_EV,
      RP + B1, VALS, ws + O_H2, ws + O_H2, NN2);

  // ================= layer 2 =================
  mfma_gemm4_kernel<<<(NN2 + 63) / 64, 256, 0, stream>>>(
      ws + O_H2, nullptr, nullptr, WPREP,
      5, 6, 7, 8,
      ws + O_K2, ws + O_V2, ws + O_Q2, ws + O_S2,
      NN2, NN2, NN3, NN3, nullptr);

  attn_kernel<<<(NN3 + 3) / 4, 256, 0, stream>>>(
      ws + O_Q2, ws + O_K2, ws + O_V2, nullptr, nullptr,
      RP + B2, VALS, ws + O_S2, (float*)d_out, NN3);

  (void)in_sizes; (void)n_in; (void)out_size; (void)ws_size;
}

// Round 6
// 602.047 us; speedup vs baseline: 1.0078x; 1.0078x over previous
//
#include <hip/hip_runtime.h>
#include <math.h>

// ---------------- problem constants ----------------
#define DD 128
#define SPLIT 50000
#define NN1 50000
#define NN2 30000
#define NN3 10000
#define EE0 500000
#define EE1 300000
#define EE2 100000
#define EALL (EE0 + EE1 + EE2)
#define NALL (NN1 + NN2 + NN3)   // 90000
#define B1 50000
#define B2 80000
#define NEG 0.2f

typedef __attribute__((ext_vector_type(8))) short bf16x8;
typedef __attribute__((ext_vector_type(4))) float f32x4;

// round-to-nearest-even f32 -> bf16 bits
static __device__ __forceinline__ unsigned short f2bf(float x) {
  unsigned u = __float_as_uint(x);
  unsigned r = (u + 0x7FFFu + ((u >> 16) & 1u)) >> 16;
  return (unsigned short)r;
}
static __device__ __forceinline__ float bf2f(unsigned short b) {
  return __uint_as_float(((unsigned)b) << 16);
}

// ================= fused CSR build (3 graphs concatenated) =================
__global__ __launch_bounds__(256) void hist_kernel(
    const int* __restrict__ dst0, const int* __restrict__ dst1,
    const int* __restrict__ dst2, int* __restrict__ counts)
{
  for (int e = blockIdx.x * 256 + threadIdx.x; e < EALL; e += gridDim.x * 256) {
    int d;
    if (e < EE0) d = dst0[e];
    else if (e < EE0 + EE1) d = B1 + dst1[e - EE0];
    else d = B2 + dst2[e - EE0 - EE1];
    atomicAdd(&counts[d], 1);
  }
}

__global__ __launch_bounds__(256) void scan1_kernel(
    const int* __restrict__ counts, int* __restrict__ rp1,
    int* __restrict__ partial, int n)
{
  __shared__ int s[256];
  int t = threadIdx.x;
  int i = blockIdx.x * 256 + t;
  int v = (i < n) ? counts[i] : 0;
  s[t] = v; __syncthreads();
  for (int off = 1; off < 256; off <<= 1) {
    int tv = (t >= off) ? s[t - off] : 0;
    __syncthreads();
    s[t] += tv;
    __syncthreads();
  }
  if (i < n) rp1[i] = s[t];
  if (t == 255) partial[blockIdx.x] = s[255];
}

__global__ __launch_bounds__(256) void scan2_kernel(int* __restrict__ partial, int nb)
{
  __shared__ int s[256];
  int t = threadIdx.x;
  int carry = 0;
  for (int base = 0; base < nb; base += 256) {
    int i = base + t;
    int v = (i < nb) ? partial[i] : 0;
    s[t] = v; __syncthreads();
    for (int off = 1; off < 256; off <<= 1) {
      int tv = (t >= off) ? s[t - off] : 0;
      __syncthreads();
      s[t] += tv;
      __syncthreads();
    }
    int ex = carry + ((t == 0) ? 0 : s[t - 1]);
    if (i < nb) partial[i] = ex;
    int tot = s[255];
    __syncthreads();
    carry += tot;
  }
}

__global__ __launch_bounds__(256) void scan3_kernel(
    int* __restrict__ rp, const int* __restrict__ partial, int n)
{
  int i = blockIdx.x * 256 + threadIdx.x;
  if (i < n) rp[i + 1] += partial[i >> 8];
  if (i == 0) rp[0] = 0;
}

__global__ __launch_bounds__(256) void fill_kernel(
    const int* __restrict__ dst0, const int* __restrict__ src0,
    const int* __restrict__ dst1, const int* __restrict__ src1,
    const int* __restrict__ dst2, const int* __restrict__ src2,
    const int* __restrict__ etyp, int* __restrict__ cursor,
    int* __restrict__ vals)
{
  for (int e = blockIdx.x * 256 + threadIdx.x; e < EALL; e += gridDim.x * 256) {
    int d, v;
    if (e < EE0) { d = dst0[e]; v = src0[e]; }
    else if (e < EE0 + EE1) {
      int k = e - EE0;
      d = B1 + dst1[k]; v = src1[k] | (etyp[k] << 17);
    } else {
      int k = e - EE0 - EE1;
      d = B2 + dst2[k]; v = src2[k];
    }
    int slot = atomicAdd(&cursor[d], 1);
    vals[slot] = v;
  }
}

// ================= weight prep: W[128][128] f32 -> transposed hi/lo bf16 =======
struct W9 { const float* w[9]; };
__global__ __launch_bounds__(256) void wprep_kernel(W9 srcs, unsigned short* out)
{
  int m = blockIdx.y;
  const float* W = srcs.w[m];
  unsigned short* hi = out + (size_t)m * 32768;
  unsigned short* lo = hi + 16384;
  for (int i = blockIdx.x * 256 + threadIdx.x; i < 16384; i += gridDim.x * 256) {
    int k = i >> 7, c = i & 127;
    float a = W[i];
    unsigned short h = f2bf(a);
    hi[c * DD + k] = h;
    lo[c * DD + k] = f2bf(a - bf2f(h));
  }
}

// ================= layer 0: CSR gather-sum of x rows (4 rows in flight) =========
__global__ __launch_bounds__(256) void agg0_kernel(
    const float* __restrict__ x, const int* __restrict__ rp,
    const int* __restrict__ vals, float* __restrict__ acc, float* __restrict__ deg)
{
  int d = blockIdx.x * 4 + (threadIdx.x >> 6);
  if (d >= NN1) return;
  int lane = threadIdx.x & 63;
  int l32 = lane & 31, half = lane >> 5;
  int beg = rp[d], end = rp[d + 1];
  const float4* x4 = (const float4*)x;
  float4 a0 = {0.f, 0.f, 0.f, 0.f}, a1 = {0.f, 0.f, 0.f, 0.f};
  int j = beg + half;
  // 4 gathers in flight per half-wave, branchless (row 0 * mask for hyper-edges)
  for (; j + 6 < end; j += 8) {
    int s0 = vals[j], s1 = vals[j + 2], s2 = vals[j + 4], s3 = vals[j + 6];
    int i0 = s0 - SPLIT, i1 = s1 - SPLIT, i2 = s2 - SPLIT, i3 = s3 - SPLIT;
    float m0 = i0 >= 0 ? 1.f : 0.f; i0 = i0 >= 0 ? i0 : 0;
    float m1 = i1 >= 0 ? 1.f : 0.f; i1 = i1 >= 0 ? i1 : 0;
    float m2 = i2 >= 0 ? 1.f : 0.f; i2 = i2 >= 0 ? i2 : 0;
    float m3 = i3 >= 0 ? 1.f : 0.f; i3 = i3 >= 0 ? i3 : 0;
    float4 v0 = x4[(size_t)i0 * 32 + l32];
    float4 v1 = x4[(size_t)i1 * 32 + l32];
    float4 v2 = x4[(size_t)i2 * 32 + l32];
    float4 v3 = x4[(size_t)i3 * 32 + l32];
    a0.x = fmaf(m0, v0.x, a0.x); a0.y = fmaf(m0, v0.y, a0.y);
    a0.z = fmaf(m0, v0.z, a0.z); a0.w = fmaf(m0, v0.w, a0.w);
    a1.x = fmaf(m1, v1.x, a1.x); a1.y = fmaf(m1, v1.y, a1.y);
    a1.z = fmaf(m1, v1.z, a1.z); a1.w = fmaf(m1, v1.w, a1.w);
    a0.x = fmaf(m2, v2.x, a0.x); a0.y = fmaf(m2, v2.y, a0.y);
    a0.z = fmaf(m2, v2.z, a0.z); a0.w = fmaf(m2, v2.w, a0.w);
    a1.x = fmaf(m3, v3.x, a1.x); a1.y = fmaf(m3, v3.y, a1.y);
    a1.z = fmaf(m3, v3.z, a1.z); a1.w = fmaf(m3, v3.w, a1.w);
  }
  for (; j < end; j += 2) {
    int s0 = vals[j];
    if (s0 >= SPLIT) {
      float4 v = x4[(size_t)(s0 - SPLIT) * 32 + l32];
      a0.x += v.x; a0.y += v.y; a0.z += v.z; a0.w += v.w;
    }
  }
  a0.x += a1.x; a0.y += a1.y; a0.z += a1.z; a0.w += a1.w;
  a0.x += __shfl(a0.x, l32 + 32);
  a0.y += __shfl(a0.y, l32 + 32);
  a0.z += __shfl(a0.z, l32 + 32);
  a0.w += __shfl(a0.w, l32 + 32);
  if (half == 0) {
    ((float4*)acc)[(size_t)d * 32 + l32] = a0;
    if (l32 == 0) deg[d] = (float)(end - beg);
  }
}

// ---- f32 LDS GEMM kept only for the two 65-row table projections ----
__global__ __launch_bounds__(256) void gemm128_kernel(
    const float* __restrict__ A, const float* __restrict__ W,
    float* __restrict__ C, int N, const float* __restrict__ deg)
{
  __shared__ float Al[64 * 128];
  __shared__ float Wl[64 * 128];
  int t = threadIdx.x;
  int cg = t & 31;
  int rg = t >> 5;
  int r0 = blockIdx.x << 6;
  int nrows = N - r0; if (nrows > 64) nrows = 64;

  const float4* Ag = (const float4*)(A + (size_t)r0 * DD);
  float4* Al4 = (float4*)Al;
  for (int i = t; i < nrows * 32; i += 256) Al4[i] = Ag[i];

  float acc[8][4] = {};
  const float4* W4 = (const float4*)W;
  float4* Wl4 = (float4*)Wl;
  const float4* Al4c = (const float4*)Al;

  for (int half = 0; half < 2; ++half) {
    __syncthreads();
    for (int i = t; i < 2048; i += 256) Wl4[i] = W4[half * 2048 + i];
    __syncthreads();
    const float4* Wl4c = (const float4*)Wl;
    int kb4 = half * 16;
    for (int k4 = 0; k4 < 16; ++k4) {
      float4 w0 = Wl4c[(k4 * 4 + 0) * 32 + cg];
      float4 w1 = Wl4c[(k4 * 4 + 1) * 32 + cg];
      float4 w2 = Wl4c[(k4 * 4 + 2) * 32 + cg];
      float4 w3 = Wl4c[(k4 * 4 + 3) * 32 + cg];
#pragma unroll
      for (int r = 0; r < 8; ++r) {
        float4 a = Al4c[(rg * 8 + r) * 32 + kb4 + k4];
        acc[r][0] = fmaf(a.x, w0.x, acc[r][0]);
        acc[r][1] = fmaf(a.x, w0.y, acc[r][1]);
        acc[r][2] = fmaf(a.x, w0.z, acc[r][2]);
        acc[r][3] = fmaf(a.x, w0.w, acc[r][3]);
        acc[r][0] = fmaf(a.y, w1.x, acc[r][0]);
        acc[r][1] = fmaf(a.y, w1.y, acc[r][1]);
        acc[r][2] = fmaf(a.y, w1.z, acc[r][2]);
        acc[r][3] = fmaf(a.y, w1.w, acc[r][3]);
        acc[r][0] = fmaf(a.z, w2.x, acc[r][0]);
        acc[r][1] = fmaf(a.z, w2.y, acc[r][1]);
        acc[r][2] = fmaf(a.z, w2.z, acc[r][2]);
        acc[r][3] = fmaf(a.z, w2.w, acc[r][3]);
        acc[r][0] = fmaf(a.w, w3.x, acc[r][0]);
        acc[r][1] = fmaf(a.w, w3.y, acc[r][1]);
        acc[r][2] = fmaf(a.w, w3.z, acc[r][2]);
        acc[r][3] = fmaf(a.w, w3.w, acc[r][3]);
      }
    }
  }

#pragma unroll
  for (int r = 0; r < 8; ++r) {
    int rr = rg * 8 + r;
    if (rr < nrows) {
      float sc = 1.0f;
      if (deg) sc = 0.5f / (deg[r0 + rr] + 1e-16f);
      float4 o;
      o.x = acc[r][0] * sc; o.y = acc[r][1] * sc;
      o.z = acc[r][2] * sc; o.w = acc[r][3] * sc;
      ((float4*)(C + (size_t)(r0 + rr) * DD))[cg] = o;
    }
  }
}

// ======== MFMA split-bf16 GEMM, tiled over (row, col) for occupancy ========
// Block = 64 rows x (ctPerBlock*16) cols of ONE output.
// gridDim.y = nouts * (8/ctPerBlock). Swapped operands: D[c][r] -> float4 row stores.
struct GemmOuts { int widx[4]; float* C[4]; int N[4]; };
__global__ __launch_bounds__(256) void mfma_gemm_kernel(
    const float* __restrict__ A,
    const float* __restrict__ SC, const float* __restrict__ SH,
    const unsigned short* __restrict__ WP,
    GemmOuts outs, int tilesPerOut, int ctPerBlock,
    const float* __restrict__ deg)
{
  int out = blockIdx.y / tilesPerOut;
  int N = outs.N[out];
  int r0 = blockIdx.x << 6;
  if (r0 >= N) return;
  float* C = outs.C[out];
  int ctOff = (blockIdx.y % tilesPerOut) * ctPerBlock;

  int t = threadIdx.x;
  int l = t & 63;
  int wl = t >> 6;
  int l15 = l & 15;
  int rbase = r0 + wl * 16 + l15;
  int r_ld = rbase < N ? rbase : (N - 1);
  int kg = (l >> 4) << 3;          // 0/8/16/24 within 32-k step

  // load + (optional BN) + split A fragments for 4 k-steps
  bf16x8 Ah[4], Al[4];
#pragma unroll
  for (int ks = 0; ks < 4; ++ks) {
    int k0 = ks * 32 + kg;
    const float4* ap = (const float4*)(A + (size_t)r_ld * DD + k0);
    float4 x0 = ap[0], x1 = ap[1];
    float av[8] = {x0.x, x0.y, x0.z, x0.w, x1.x, x1.y, x1.z, x1.w};
    if (SC) {
      const float4* scp = (const float4*)(SC + k0);
      const float4* shp = (const float4*)(SH + k0);
      float4 s0 = scp[0], s1 = scp[1], h0 = shp[0], h1 = shp[1];
      av[0] = fmaf(av[0], s0.x, h0.x);
      av[1] = fmaf(av[1], s0.y, h0.y);
      av[2] = fmaf(av[2], s0.z, h0.z);
      av[3] = fmaf(av[3], s0.w, h0.w);
      av[4] = fmaf(av[4], s1.x, h1.x);
      av[5] = fmaf(av[5], s1.y, h1.y);
      av[6] = fmaf(av[6], s1.z, h1.z);
      av[7] = fmaf(av[7], s1.w, h1.w);
    }
#pragma unroll
    for (int j = 0; j < 8; ++j) {
      unsigned short h = f2bf(av[j]);
      Ah[ks][j] = (short)h;
      Al[ks][j] = (short)f2bf(av[j] - bf2f(h));
    }
  }

  const unsigned short* Wh = WP + (size_t)outs.widx[out] * 32768;
  const unsigned short* Wl = Wh + 16384;

  float dsc = 1.0f;
  if (deg && out == 0) dsc = 0.5f / (deg[r_ld] + 1e-16f);
  bool doStore = rbase < N;

  for (int ct = 0; ct < ctPerBlock; ++ct) {
    int col = (ctOff + ct) * 16 + l15;
    const unsigned short* whp = Wh + (size_t)col * DD + kg;
    const unsigned short* wlp = Wl + (size_t)col * DD + kg;
    bf16x8 bh0 = *(const bf16x8*)(whp);
    bf16x8 bh1 = *(const bf16x8*)(whp + 32);
    bf16x8 bh2 = *(const bf16x8*)(whp + 64);
    bf16x8 bh3 = *(const bf16x8*)(whp + 96);
    bf16x8 bl0 = *(const bf16x8*)(wlp);
    bf16x8 bl1 = *(const bf16x8*)(wlp + 32);
    bf16x8 bl2 = *(const bf16x8*)(wlp + 64);
    bf16x8 bl3 = *(const bf16x8*)(wlp + 96);
    f32x4 acc = (f32x4){0.f, 0.f, 0.f, 0.f};
    acc = __builtin_amdgcn_mfma_f32_16x16x32_bf16(bh0, Ah[0], acc, 0, 0, 0);
    acc = __builtin_amdgcn_mfma_f32_16x16x32_bf16(bl0, Ah[0], acc, 0, 0, 0);
    acc = __builtin_amdgcn_mfma_f32_16x16x32_bf16(bh0, Al[0], acc, 0, 0, 0);
    acc = __builtin_amdgcn_mfma_f32_16x16x32_bf16(bh1, Ah[1], acc, 0, 0, 0);
    acc = __builtin_amdgcn_mfma_f32_16x16x32_bf16(bl1, Ah[1], acc, 0, 0, 0);
    acc = __builtin_amdgcn_mfma_f32_16x16x32_bf16(bh1, Al[1], acc, 0, 0, 0);
    acc = __builtin_amdgcn_mfma_f32_16x16x32_bf16(bh2, Ah[2], acc, 0, 0, 0);
    acc = __builtin_amdgcn_mfma_f32_16x16x32_bf16(bl2, Ah[2], acc, 0, 0, 0);
    acc = __builtin_amdgcn_mfma_f32_16x16x32_bf16(bh2, Al[2], acc, 0, 0, 0);
    acc = __builtin_amdgcn_mfma_f32_16x16x32_bf16(bh3, Ah[3], acc, 0, 0, 0);
    acc = __builtin_amdgcn_mfma_f32_16x16x32_bf16(bl3, Ah[3], acc, 0, 0, 0);
    acc = __builtin_amdgcn_mfma_f32_16x16x32_bf16(bh3, Al[3], acc, 0, 0, 0);
    if (doStore) {
      // D[c][r]: lane holds row = l&15, cols = (ctOff+ct)*16 + (l>>4)*4 + 0..3
      int colbase = (ctOff + ct) * 16 + ((l >> 4) << 2);
      f32x4 o;
      o[0] = acc[0] * dsc; o[1] = acc[1] * dsc;
      o[2] = acc[2] * dsc; o[3] = acc[3] * dsc;
      *(f32x4*)(C + (size_t)rbase * DD + colbase) = o;
    }
  }
}

// ---------------- BatchNorm stats + finalize ----------------
__global__ __launch_bounds__(256) void bn_stats_kernel(
    const float* __restrict__ H, float* __restrict__ sums)
{
  int t = threadIdx.x;
  int col = t & 127;
  float s = 0.f, q = 0.f;
  for (int r = blockIdx.x * 2 + (t >> 7); r < NN1; r += gridDim.x * 2) {
    float v = H[(size_t)r * DD + col];
    s += v; q += v * v;
  }
  __shared__ float ls[256], lq[256];
  ls[t] = s; lq[t] = q;
  __syncthreads();
  if (t < 128) {
    atomicAdd(&sums[col], ls[t] + ls[t + 128]);
    atomicAdd(&sums[128 + col], lq[t] + lq[t + 128]);
  }
}

__global__ __launch_bounds__(128) void bn_finalize_kernel(
    const float* __restrict__ sums, const float* __restrict__ g,
    const float* __restrict__ b, float* __restrict__ SC, float* __restrict__ SH)
{
  int c = threadIdx.x;
  const float invN = 1.0f / (float)NN1;
  float mu = sums[c] * invN;
  float var = sums[128 + c] * invN - mu * mu;
  float rs = rsqrtf(var + 1e-5f);
  float sc = rs * g[c];
  SC[c] = sc;
  SH[c] = b[c] - mu * sc;
}

// ========== fused flash-attention over value-CSR ==========
__global__ __launch_bounds__(256) void attn_kernel(
    const float* __restrict__ Q, const float* __restrict__ K,
    const float* __restrict__ V, const float* __restrict__ EKT,
    const float* __restrict__ EVT, const int* __restrict__ rp,
    const int* __restrict__ vals, const float* __restrict__ Spre,
    float* __restrict__ Out, int Nt)
{
  int d = blockIdx.x * 4 + (threadIdx.x >> 6);
  if (d >= Nt) return;
  int lane = threadIdx.x & 63;
  int l32 = lane & 31, half = lane >> 5;

  const float4* Q4 = (const float4*)Q;
  const float4* K4 = (const float4*)K;
  const float4* V4 = (const float4*)V;
  float4 q = Q4[(size_t)d * 32 + l32];

  float m = -INFINITY, ss = 0.f;
  float4 o = {0.f, 0.f, 0.f, 0.f};

  int beg = rp[d], end = rp[d + 1];
  for (int j = beg + half; j < end; j += 2) {
    int pv = vals[j];
    float4 kk, vv;
    if (EKT) {
      int s = pv & 0x1FFFF, ty = pv >> 17;
      kk = K4[(size_t)s * 32 + l32];
      vv = V4[(size_t)s * 32 + l32];
      float4 ek = ((const float4*)EKT)[(size_t)ty * 32 + l32];
      float4 ev = ((const float4*)EVT)[(size_t)ty * 32 + l32];
      kk.x += ek.x; kk.y += ek.y; kk.z += ek.z; kk.w += ek.w;
      vv.x += ev.x; vv.y += ev.y; vv.z += ev.z; vv.w += ev.w;
    } else {
      kk = K4[(size_t)pv * 32 + l32];
      vv = V4[(size_t)pv * 32 + l32];
    }
    float p = q.x * kk.x + q.y * kk.y + q.z * kk.z + q.w * kk.w;
    p += __shfl_xor(p, 1);
    p += __shfl_xor(p, 2);
    float lg = p * 0.25f;
    lg = (lg >= 0.f) ? lg : NEG * lg;
    float nm = fmaxf(m, lg);
    float w = __expf(m - nm);
    float a = __expf(lg - nm);
    ss = ss * w + a;
    o.x = o.x * w + a * vv.x;
    o.y = o.y * w + a * vv.y;
    o.z = o.z * w + a * vv.z;
    o.w = o.w * w + a * vv.w;
    m = nm;
  }

  float mp = __shfl_xor(m, 32);
  float sp = __shfl_xor(ss, 32);
  float4 op;
  op.x = __shfl_xor(o.x, 32);
  op.y = __shfl_xor(o.y, 32);
  op.z = __shfl_xor(o.z, 32);
  op.w = __shfl_xor(o.w, 32);
  float nm = fmaxf(m, mp);
  if (nm == -INFINITY) nm = 0.f;
  float w = __expf(m - nm);
  float wp = __expf(mp - nm);
  float sT = ss * w + sp * wp;
  float inv = 1.0f / (sT + 1e-16f);
  float4 res;
  res.x = (o.x * w + op.x * wp) * inv;
  res.y = (o.y * w + op.y * wp) * inv;
  res.z = (o.z * w + op.z * wp) * inv;
  res.w = (o.w * w + op.w * wp) * inv;

  if (half == 0) {
    float4 sr = ((const float4*)Spre)[(size_t)d * 32 + l32];
    float4 ot;
    ot.x = 0.5f * (sr.x + res.x);
    ot.y = 0.5f * (sr.y + res.y);
    ot.z = 0.5f * (sr.z + res.z);
    ot.w = 0.5f * (sr.w + res.w);
    ((float4*)Out)[(size_t)d * 32 + l32] = ot;
  }
}

extern "C" void kernel_launch(void* const* d_in, const int* in_sizes, int n_in,
                              void* d_out, int out_size, void* d_ws, size_t ws_size,
                              hipStream_t stream)
{
  const float* x   = (const float*)d_in[0];
  const float* tt  = (const float*)d_in[1];
  const float* at  = (const float*)d_in[2];
  const float* Wv0 = (const float*)d_in[5];
  const float* Wq1 = (const float*)d_in[7];
  const float* Wk1 = (const float*)d_in[8];
  const float* Wv1 = (const float*)d_in[9];
  const float* Ws1 = (const float*)d_in[10];
  const float* Wek1= (const float*)d_in[11];
  const float* Wev1= (const float*)d_in[12];
  const float* Wq2 = (const float*)d_in[13];
  const float* Wk2 = (const float*)d_in[14];
  const float* Wv2 = (const float*)d_in[15];
  const float* Ws2 = (const float*)d_in[16];
  const float* g0  = (const float*)d_in[17];
  const float* b0  = (const float*)d_in[18];
  const int* src0 = (const int*)d_in[19];
  const int* dst0 = (const int*)d_in[20];
  const int* src1 = (const int*)d_in[21];
  const int* dst1 = (const int*)d_in[22];
  const int* src2 = (const int*)d_in[23];
  const int* dst2 = (const int*)d_in[24];
  const int* etyp = (const int*)d_in[25];

  float* ws = (float*)d_ws;

  // ---- float workspace layout ----
  const size_t O_K1  = 0;          // 6.40M : acc0, then k1
  const size_t O_V1  = 6400000;    // 6.40M : v1
  const size_t O_Q1  = 12800000;   // 3.84M : q1
  const size_t O_H2  = 16640000;   // 3.84M : s1 prefill -> h2 (attn in place)
  const size_t O_DEG = 20480000;   // 50K
  const size_t O_EK  = 20530000;   // 8320
  const size_t O_EV  = 20538320;   // 8320
  const size_t O_BN  = 20546640;   // 256
  const size_t O_SC  = 20546896;   // 128
  const size_t O_SH  = 20547024;   // 128
  const size_t O_H1  = 20547152;   // 6.40M -> end 26,947,152
  // layer-2 overlays:
  const size_t O_K2  = 0;          // 3.84M
  const size_t O_V2  = 3840000;    // 3.84M
  const size_t O_Q2  = 7680000;    // 1.28M
  const size_t O_S2  = 8960000;    // 1.28M
  // ---- int workspace ----
  int* wi   = (int*)(ws + 26947152);
  int* RP   = wi;                  // 90001
  int* VALS = wi + 90001;          // 900000
  int* CNT  = wi + 990001;         // 90000
  int* PART = wi + 1080001;        // 512
  unsigned short* WPREP = (unsigned short*)(wi + 1080520); // 9*32768 ushort

  // ================= weight prep (9 matrices) =================
  // idx: 0 Wv0 | 1 Wk1 2 Wv1 3 Wq1 4 Ws1 | 5 Wk2 6 Wv2 7 Wq2 8 Ws2
  W9 w9;
  w9.w[0] = Wv0;
  w9.w[1] = Wk1; w9.w[2] = Wv1; w9.w[3] = Wq1; w9.w[4] = Ws1;
  w9.w[5] = Wk2; w9.w[6] = Wv2; w9.w[7] = Wq2; w9.w[8] = Ws2;
  wprep_kernel<<<dim3(8, 9), 256, 0, stream>>>(w9, WPREP);

  // ================= fused CSR build =================
  hipMemsetAsync(CNT, 0, (size_t)NALL * 4, stream);
  hist_kernel<<<3516, 256, 0, stream>>>(dst0, dst1, dst2, CNT);
  int nb = (NALL + 255) / 256;     // 352
  scan1_kernel<<<nb, 256, 0, stream>>>(CNT, RP + 1, PART, NALL);
  scan2_kernel<<<1, 256, 0, stream>>>(PART, nb);
  scan3_kernel<<<nb, 256, 0, stream>>>(RP, PART, NALL);
  hipMemcpyAsync(CNT, RP, (size_t)NALL * 4, hipMemcpyDeviceToDevice, stream);
  fill_kernel<<<3516, 256, 0, stream>>>(dst0, src0, dst1, src1, dst2, src2,
                                        etyp, CNT, VALS);

  hipMemsetAsync(ws + O_BN, 0, (size_t)256 * 4, stream);

  // ================= layer 0 =================
  agg0_kernel<<<(NN1 + 3) / 4, 256, 0, stream>>>(x, RP, VALS, ws + O_K1, ws + O_DEG);
  // h1 = 0.5*(acc0 @ Wv0)/(deg+1e-16) ; 64-col tiles (tilesPerOut=2)
  {
    GemmOuts o{};
    o.widx[0] = 0; o.C[0] = ws + O_H1; o.N[0] = NN1;
    mfma_gemm_kernel<<<dim3((NN1 + 63) / 64, 2), 256, 0, stream>>>(
        ws + O_K1, nullptr, nullptr, WPREP, o, 2, 4, ws + O_DEG);
  }
  bn_stats_kernel<<<512, 256, 0, stream>>>(ws + O_H1, ws + O_BN);
  bn_finalize_kernel<<<1, 128, 0, stream>>>(ws + O_BN, g0, b0, ws + O_SC, ws + O_SH);

  // ================= layer 1 (BN folded into A); 128-col tiles =================
  {
    GemmOuts o{};
    o.widx[0] = 1; o.C[0] = ws + O_K1; o.N[0] = NN1;
    o.widx[1] = 2; o.C[1] = ws + O_V1; o.N[1] = NN1;
    o.widx[2] = 3; o.C[2] = ws + O_Q1; o.N[2] = NN2;
    o.widx[3] = 4; o.C[3] = ws + O_H2; o.N[3] = NN2;
    mfma_gemm_kernel<<<dim3((NN1 + 63) / 64, 4), 256, 0, stream>>>(
        ws + O_H1, ws + O_SC, ws + O_SH, WPREP, o, 1, 8, nullptr);
  }
  gemm128_kernel<<<2, 256, 0, stream>>>(tt, Wek1, ws + O_EK, 65, nullptr);
  gemm128_kernel<<<2, 256, 0, stream>>>(at, Wev1, ws + O_EV, 65, nullptr);

  attn_kernel<<<(NN2 + 3) / 4, 256, 0, stream>>>(
      ws + O_Q1, ws + O_K1, ws + O_V1, ws + O_EK, ws + O_EV,
      RP + B1, VALS, ws + O_H2, ws + O_H2, NN2);

  // ================= layer 2; 128-col tiles =================
  {
    GemmOuts o{};
    o.widx[0] = 5; o.C[0] = ws + O_K2; o.N[0] = NN2;
    o.widx[1] = 6; o.C[1] = ws + O_V2; o.N[1] = NN2;
    o.widx[2] = 7; o.C[2] = ws + O_Q2; o.N[2] = NN3;
    o.widx[3] = 8; o.C[3] = ws + O_S2; o.N[3] = NN3;
    mfma_gemm_kernel<<<dim3((NN2 + 63) / 64, 4), 256, 0, stream>>>(
        ws + O_H2, nullptr, nullptr, WPREP, o, 1, 8, nullptr);
  }

  attn_kernel<<<(NN3 + 3) / 4, 256, 0, stream>>>(
      ws + O_Q2, ws + O_K2, ws + O_V2, nullptr, nullptr,
      RP + B2, VALS, ws + O_S2, (float*)d_out, NN3);

  (void)in_sizes; (void)n_in; (void)out_size; (void)ws_size;
}